// Round 5
// baseline (484.197 us; speedup 1.0000x reference)
//
#include <hip/hip_runtime.h>
#include <math.h>

constexpr int NN   = 100000;
constexpr int NE   = 1600000;
constexpr int FIN  = 256;
constexpr int HID  = 64;
constexpr int FOUT = 40;
constexpr float SLOPE = 0.2f;
constexpr int NB    = (NN + 255) / 256;   // 391 node-scan blocks == bucket count
constexpr int NBUCK = NB;                 // bucket = dst >> 8 (256 nodes/bucket)
constexpr int TILE_A = 8192;              // edges per partition-A workgroup
constexpr int NWG_A = (NE + TILE_A - 1) / TILE_A;  // 196
constexpr int APAD = 68;                  // sA row stride in floats (17 float4s)

// ---------------- GEMM1: z = feat @ W1, fused el/er + dst histogram --------
// 64-node x 64-col tile, K=256 in 4 slices of 64. 256 thr, 4x4 per thread.
// Inner loop chunked by 4 k's: all LDS reads are ds_read_b128
// (8 b128 = ~96 LDS-cyc vs 64 FMA = 128 VALU-cyc per chunk -> VALU-bound).
__global__ __launch_bounds__(256, 4) void gemm1_kernel(
    const float* __restrict__ feat, const float* __restrict__ W1,
    const float* __restrict__ al, const float* __restrict__ ar,
    const int* __restrict__ dst, int* __restrict__ deg,
    float* __restrict__ z, float* __restrict__ el, float* __restrict__ er)
{
    // fused histogram: 1563 blocks * 256 thr * 4 edges >= NE
    {
        int base = (blockIdx.x * 256 + threadIdx.x) * 4;
        if (base < NE) {  // NE % 4 == 0
            const int4 d4 = *(const int4*)&dst[base];
            atomicAdd(&deg[d4.x], 1); atomicAdd(&deg[d4.y], 1);
            atomicAdd(&deg[d4.z], 1); atomicAdd(&deg[d4.w], 1);
        }
    }

    __shared__ float sA[64 * APAD];   // A: [node][k], stride 68
    __shared__ float sB[64 * 64];     // B: [k][c]
    const int t  = threadIdx.x;
    const int tm = t >> 4;            // 0..15 -> nodes 4*tm..4*tm+3
    const int tc = t & 15;            // 0..15 -> cols  4*tc..4*tc+3
    const int ntile = blockIdx.x * 64;

    float acc[4][4] = {};

    for (int kt = 0; kt < 4; ++kt) {
        // stage A: direct float4 copy, no transpose
        #pragma unroll
        for (int i = 0; i < 4; ++i) {
            int nloc = tm + 16 * i;
            int n = ntile + nloc; if (n >= NN) n = NN - 1;
            float4 f = *(const float4*)&feat[(size_t)n * FIN + kt * 64 + tc * 4];
            *(float4*)&sA[nloc * APAD + tc * 4] = f;
        }
        // stage B slice (contiguous 4096 floats)
        #pragma unroll
        for (int i = 0; i < 4; ++i) {
            int vec = t + 256 * i;
            *(float4*)&sB[vec * 4] = *(const float4*)&W1[kt * 4096 + vec * 4];
        }
        __syncthreads();

        #pragma unroll 4
        for (int k4 = 0; k4 < 16; ++k4) {
            float4 a0 = *(const float4*)&sA[(4 * tm + 0) * APAD + 4 * k4];
            float4 a1 = *(const float4*)&sA[(4 * tm + 1) * APAD + 4 * k4];
            float4 a2 = *(const float4*)&sA[(4 * tm + 2) * APAD + 4 * k4];
            float4 a3 = *(const float4*)&sA[(4 * tm + 3) * APAD + 4 * k4];
            float4 b0 = *(const float4*)&sB[(4 * k4 + 0) * 64 + 4 * tc];
            float4 b1 = *(const float4*)&sB[(4 * k4 + 1) * 64 + 4 * tc];
            float4 b2 = *(const float4*)&sB[(4 * k4 + 2) * 64 + 4 * tc];
            float4 b3 = *(const float4*)&sB[(4 * k4 + 3) * 64 + 4 * tc];
            #pragma unroll
            for (int i = 0; i < 4; ++i) {
                const float4 ai = (i == 0) ? a0 : (i == 1) ? a1 : (i == 2) ? a2 : a3;
                acc[i][0] += ai.x * b0.x + ai.y * b1.x + ai.z * b2.x + ai.w * b3.x;
                acc[i][1] += ai.x * b0.y + ai.y * b1.y + ai.z * b2.y + ai.w * b3.y;
                acc[i][2] += ai.x * b0.z + ai.y * b1.z + ai.z * b2.z + ai.w * b3.z;
                acc[i][3] += ai.x * b0.w + ai.y * b1.w + ai.z * b2.w + ai.w * b3.w;
            }
        }
        __syncthreads();
    }

    float alv[4], arv[4];
    #pragma unroll
    for (int j = 0; j < 4; ++j) { alv[j] = al[4 * tc + j]; arv[j] = ar[4 * tc + j]; }

    #pragma unroll
    for (int i = 0; i < 4; ++i) {
        int n = ntile + 4 * tm + i;
        float pl = acc[i][0] * alv[0] + acc[i][1] * alv[1] + acc[i][2] * alv[2] + acc[i][3] * alv[3];
        float pr = acc[i][0] * arv[0] + acc[i][1] * arv[1] + acc[i][2] * arv[2] + acc[i][3] * arv[3];
        #pragma unroll
        for (int off = 8; off >= 1; off >>= 1) {
            pl += __shfl_xor(pl, off);
            pr += __shfl_xor(pr, off);
        }
        if (n < NN) {
            float4 zv = make_float4(acc[i][0], acc[i][1], acc[i][2], acc[i][3]);
            *(float4*)&z[(size_t)n * HID + 4 * tc] = zv;
            if (tc == 0) { el[n] = pl; er[n] = pr; }
        }
    }
}

// ---------------- GEMM2: z2 = h @ W2, fused el2/er2 ------------------------
__global__ __launch_bounds__(256) void gemm2_kernel(
    const float* __restrict__ h, const float* __restrict__ W2,
    const float* __restrict__ al, const float* __restrict__ ar,
    float* __restrict__ z2, float* __restrict__ el, float* __restrict__ er)
{
    __shared__ float sh[4][64];
    const int w = threadIdx.x >> 6, lane = threadIdx.x & 63;
    const int n = blockIdx.x * 4 + w;          // NN % 4 == 0
    sh[w][lane] = h[(size_t)n * HID + lane];
    __syncthreads();
    float acc = 0.f;
    if (lane < FOUT) {
        #pragma unroll 8
        for (int k = 0; k < 64; ++k) acc += sh[w][k] * W2[k * FOUT + lane];
    }
    float pl = (lane < FOUT) ? acc * al[lane] : 0.f;
    float pr = (lane < FOUT) ? acc * ar[lane] : 0.f;
    #pragma unroll
    for (int off = 32; off >= 1; off >>= 1) { pl += __shfl_xor(pl, off); pr += __shfl_xor(pr, off); }
    if (lane == 0) { el[n] = pl; er[n] = pr; }
    if (lane < FOUT) z2[(size_t)n * FOUT + lane] = acc;
}

// ---------------- CSR build: scans ------------------------------------------
__global__ __launch_bounds__(256) void scan_reduce_kernel(
    const int* __restrict__ deg, int* __restrict__ bsum)
{
    __shared__ int tmp[256];
    int idx = blockIdx.x * 256 + threadIdx.x;
    int v = (idx < NN) ? deg[idx] : 0;
    tmp[threadIdx.x] = v; __syncthreads();
    for (int off = 128; off >= 1; off >>= 1) {
        if (threadIdx.x < off) tmp[threadIdx.x] += tmp[threadIdx.x + off];
        __syncthreads();
    }
    if (threadIdx.x == 0) bsum[blockIdx.x] = tmp[0];
}

__global__ __launch_bounds__(512) void scan_top_kernel(
    const int* __restrict__ bsum, int* __restrict__ bofs, int* __restrict__ row_ptr)
{
    __shared__ int tmp[512];
    int t = threadIdx.x;
    int v = (t < NB) ? bsum[t] : 0;
    tmp[t] = v; __syncthreads();
    for (int off = 1; off < 512; off <<= 1) {
        int x = (t >= off) ? tmp[t - off] : 0;
        __syncthreads();
        tmp[t] += x;
        __syncthreads();
    }
    int excl = tmp[t] - v;
    if (t < NB) bofs[t] = excl;
    if (t == NB - 1) row_ptr[NN] = excl + v;  // total = NE
}

// writes row_ptr; also bucket cursor init gcur[b] = bucket base
__global__ __launch_bounds__(256) void scan_final_kernel(
    const int* __restrict__ deg, const int* __restrict__ bofs,
    int* __restrict__ row_ptr, int* __restrict__ gcur)
{
    __shared__ int tmp[256];
    int t = threadIdx.x;
    int idx = blockIdx.x * 256 + t;
    int v = (idx < NN) ? deg[idx] : 0;
    tmp[t] = v; __syncthreads();
    for (int off = 1; off < 256; off <<= 1) {
        int x = (t >= off) ? tmp[t - off] : 0;
        __syncthreads();
        tmp[t] += x;
        __syncthreads();
    }
    if (idx < NN) row_ptr[idx] = bofs[blockIdx.x] + tmp[t] - v;
    if (t == 0) gcur[blockIdx.x] = bofs[blockIdx.x];   // block b == bucket b
}

// ---------------- Pass A: bucket partition (line-dense writes) --------------
// pack = (src << 8) | (dst & 255); bucket = dst >> 8
__global__ __launch_bounds__(256) void partitionA_kernel(
    const int* __restrict__ src, const int* __restrict__ dst,
    int* __restrict__ gcur, int* __restrict__ ebuck)
{
    __shared__ int hist[NBUCK];
    __shared__ int lcur[NBUCK];
    const int t = threadIdx.x;
    const int e0 = blockIdx.x * TILE_A;
    const int e1 = (e0 + TILE_A < NE) ? e0 + TILE_A : NE;

    for (int i = t; i < NBUCK; i += 256) hist[i] = 0;
    __syncthreads();
    for (int e = e0 + t; e < e1; e += 256)
        atomicAdd(&hist[dst[e] >> 8], 1);
    __syncthreads();
    for (int i = t; i < NBUCK; i += 256) {
        int hv = hist[i];
        lcur[i] = hv ? atomicAdd(&gcur[i], hv) : 0;
    }
    __syncthreads();
    for (int e = e0 + t; e < e1; e += 256) {
        int d = dst[e], s = src[e];
        int p = atomicAdd(&lcur[d >> 8], 1);
        ebuck[p] = (s << 8) | (d & 255);
    }
}

// ---------------- Pass B: per-bucket CSR scatter (LDS cursors) --------------
__global__ __launch_bounds__(256) void partitionB_kernel(
    const int* __restrict__ row_ptr, const int* __restrict__ ebuck,
    int* __restrict__ esrc)
{
    __shared__ int lcur[256];
    const int b = blockIdx.x;
    const int n0 = b << 8;
    const int n1 = (n0 + 256 < NN) ? n0 + 256 : NN;
    const int t = threadIdx.x;
    if (n0 + t < n1) lcur[t] = row_ptr[n0 + t];
    __syncthreads();
    const int r0 = row_ptr[n0], r1 = row_ptr[n1];
    for (int e = r0 + t; e < r1; e += 256) {
        int pk = ebuck[e];
        int p = atomicAdd(&lcur[pk & 255], 1);
        esrc[p] = pk >> 8;
    }
}

// ---------------- fused per-destination GAT gather -------------------------
template<int F, bool FINAL_LAYER>
__global__ __launch_bounds__(256) void gat_gather_kernel(
    const int* __restrict__ row_ptr, const int* __restrict__ esrc,
    const float* __restrict__ el, const float* __restrict__ er,
    const float* __restrict__ z, const float* __restrict__ bias,
    float* __restrict__ out)
{
    __shared__ float sw[4][64];
    __shared__ int   ssn[4][64];
    const int w = threadIdx.x >> 6, lane = threadIdx.x & 63;
    const int d = blockIdx.x * 4 + w;          // NN % 4 == 0
    const int r0 = row_ptr[d], r1 = row_ptr[d + 1];
    const int cnt = r1 - r0;
    const float erd = er[d];

    float accv = 0.f;
    float s = 0.f;

    if (cnt <= 64) {
        int sn = 0; float v = -INFINITY;
        if (lane < cnt) {
            sn = esrc[r0 + lane];
            v = el[sn] + erd;
            v = (v >= 0.f) ? v : SLOPE * v;
        }
        float m = v;
        #pragma unroll
        for (int off = 32; off >= 1; off >>= 1) m = fmaxf(m, __shfl_xor(m, off));
        float wv = (lane < cnt) ? __expf(v - m) : 0.f;
        s = wv;
        #pragma unroll
        for (int off = 32; off >= 1; off >>= 1) s += __shfl_xor(s, off);
        sw[w][lane] = wv; ssn[w][lane] = sn;   // wave-synchronous
        if (lane < F) {
            int j = 0;
            for (; j + 8 <= cnt; j += 8) {
                float acc0 = 0.f, acc1 = 0.f;
                #pragma unroll
                for (int q = 0; q < 8; q += 2) {
                    float wa = sw[w][j + q],     wb = sw[w][j + q + 1];
                    int   sa = ssn[w][j + q],    sb = ssn[w][j + q + 1];
                    acc0 += wa * z[(size_t)sa * F + lane];
                    acc1 += wb * z[(size_t)sb * F + lane];
                }
                accv += acc0 + acc1;
            }
            for (; j < cnt; ++j)
                accv += sw[w][j] * z[(size_t)ssn[w][j] * F + lane];
        }
    } else {
        float m = -INFINITY;
        for (int e = r0 + lane; e < r1; e += 64) {
            float v = el[esrc[e]] + erd;
            v = (v >= 0.f) ? v : SLOPE * v;
            m = fmaxf(m, v);
        }
        #pragma unroll
        for (int off = 32; off >= 1; off >>= 1) m = fmaxf(m, __shfl_xor(m, off));
        for (int base = r0; base < r1; base += 64) {
            int e = base + lane;
            float wv = 0.f; int sn = 0;
            if (e < r1) {
                sn = esrc[e];
                float v = el[sn] + erd;
                v = (v >= 0.f) ? v : SLOPE * v;
                wv = __expf(v - m);
            }
            sw[w][lane] = wv; ssn[w][lane] = sn;
            s += wv;
            int c = r1 - base; if (c > 64) c = 64;
            if (lane < F) {
                for (int j = 0; j < c; ++j)
                    accv += sw[w][j] * z[(size_t)ssn[w][j] * F + lane];
            }
        }
        #pragma unroll
        for (int off = 32; off >= 1; off >>= 1) s += __shfl_xor(s, off);
    }

    float res = (cnt > 0) ? (accv / s) : 0.f;

    if (!FINAL_LAYER) {
        if (lane < F) {
            float v = res + bias[lane];
            out[(size_t)d * F + lane] = (v > 0.f) ? v : 0.f;
        }
    } else {
        float v = (lane < F) ? res + bias[lane] : -INFINITY;
        float mx = v;
        #pragma unroll
        for (int off = 32; off >= 1; off >>= 1) mx = fmaxf(mx, __shfl_xor(mx, off));
        float ex = (lane < F) ? __expf(v - mx) : 0.f;
        float sm = ex;
        #pragma unroll
        for (int off = 32; off >= 1; off >>= 1) sm += __shfl_xor(sm, off);
        if (lane < F) out[(size_t)d * F + lane] = v - mx - __logf(sm);
    }
}

extern "C" void kernel_launch(void* const* d_in, const int* in_sizes, int n_in,
                              void* d_out, int out_size, void* d_ws, size_t ws_size,
                              hipStream_t stream) {
    const float* feat = (const float*)d_in[0];
    const int*   src  = (const int*)d_in[1];
    const int*   dst  = (const int*)d_in[2];
    const float* W1   = (const float*)d_in[3];
    const float* b1   = (const float*)d_in[4];
    const float* al1  = (const float*)d_in[5];
    const float* ar1  = (const float*)d_in[6];
    const float* W2   = (const float*)d_in[7];
    const float* b2   = (const float*)d_in[8];
    const float* al2  = (const float*)d_in[9];
    const float* ar2  = (const float*)d_in[10];
    float* out = (float*)d_out;

    float* ws    = (float*)d_ws;
    float* z1    = ws;                          // NN*64 (reused for z2)
    float* h     = z1 + (size_t)NN * HID;       // NN*64
    float* el1   = h + (size_t)NN * HID;
    float* er1   = el1 + NN;
    float* el2   = er1 + NN;
    float* er2   = el2 + NN;
    int*   deg   = (int*)(er2 + NN);            // NN
    int*   rowp  = deg + NN;                    // NN+1
    int*   bsum  = rowp + NN + 1;               // NB
    int*   bofs  = bsum + NB;                   // NB
    int*   gcur  = bofs + NB;                   // NBUCK
    int*   esrc  = gcur + NBUCK;                // NE
    int*   ebuck = (int*)h;                     // NE, dead before gather1 writes h
    float* z2    = z1;

    hipMemsetAsync(deg, 0, NN * sizeof(int), stream);

    // ---- layer-1 GEMM with fused dst-histogram ----
    gemm1_kernel<<<(NN + 63) / 64, 256, 0, stream>>>(feat, W1, al1, ar1, dst, deg, z1, el1, er1);

    // ---- CSR build ----
    scan_reduce_kernel<<<NB, 256, 0, stream>>>(deg, bsum);
    scan_top_kernel<<<1, 512, 0, stream>>>(bsum, bofs, rowp);
    scan_final_kernel<<<NB, 256, 0, stream>>>(deg, bofs, rowp, gcur);
    partitionA_kernel<<<NWG_A, 256, 0, stream>>>(src, dst, gcur, ebuck);
    partitionB_kernel<<<NBUCK, 256, 0, stream>>>(rowp, ebuck, esrc);

    // ---- layer 1 gather ----
    gat_gather_kernel<HID, false><<<NN / 4, 256, 0, stream>>>(rowp, esrc, el1, er1, z1, b1, h);

    // ---- layer 2 ----
    gemm2_kernel<<<NN / 4, 256, 0, stream>>>(h, W2, al2, ar2, z2, el2, er2);
    gat_gather_kernel<FOUT, true><<<NN / 4, 256, 0, stream>>>(rowp, esrc, el2, er2, z2, b2, out);
}

// Round 6
// 468.386 us; speedup vs baseline: 1.0338x; 1.0338x over previous
//
#include <hip/hip_runtime.h>
#include <math.h>

constexpr int NN   = 100000;
constexpr int NE   = 1600000;
constexpr int FIN  = 256;
constexpr int HID  = 64;
constexpr int FOUT = 40;
constexpr float SLOPE = 0.2f;
constexpr int NB    = (NN + 255) / 256;   // 391 node-scan blocks == bucket count
constexpr int NBUCK = NB;                 // bucket = dst >> 8 (256 nodes/bucket)
constexpr int TILE_A = 8192;              // edges per partition-A workgroup
constexpr int NWG_A = (NE + TILE_A - 1) / TILE_A;  // 196
constexpr int AK = 264;                   // LDS row stride in bf16 (256 + 8 pad)

typedef short  short8  __attribute__((ext_vector_type(8)));
typedef float  floatx4 __attribute__((ext_vector_type(4)));

__device__ inline unsigned short f2bf(float x) {   // RNE fp32->bf16
    union { float f; unsigned int u; } c; c.f = x;
    unsigned int u = c.u;
    return (unsigned short)((u + 0x7FFF + ((u >> 16) & 1)) >> 16);
}

// ---------------- W1^T bf16 prep (once per launch) --------------------------
__global__ __launch_bounds__(256) void w1t_kernel(
    const float* __restrict__ W1, unsigned short* __restrict__ W1T)
{
    int idx = blockIdx.x * 256 + threadIdx.x;       // 16384 elems
    if (idx < FIN * HID) {
        int k = idx >> 6, n = idx & 63;
        W1T[n * FIN + k] = f2bf(W1[idx]);
    }
}

// ---------------- GEMM1 via bf16 MFMA: z = feat @ W1, fused el/er + hist ----
// 64-node tile x 64 cols, K=256. 4 waves; wave w owns node rows 16w..16w+15.
// A staged fp32->bf16 in LDS [m][k] (stride 264), W1T staged bf16 [n][k].
__global__ __launch_bounds__(256) void gemm1_kernel(
    const float* __restrict__ feat, const unsigned short* __restrict__ W1T,
    const float* __restrict__ al, const float* __restrict__ ar,
    const int* __restrict__ dst, int* __restrict__ deg,
    float* __restrict__ z, float* __restrict__ el, float* __restrict__ er)
{
    // fused histogram: 1563 blocks * 256 thr * 4 edges >= NE
    {
        int base = (blockIdx.x * 256 + threadIdx.x) * 4;
        if (base < NE) {  // NE % 4 == 0
            const int4 d4 = *(const int4*)&dst[base];
            atomicAdd(&deg[d4.x], 1); atomicAdd(&deg[d4.y], 1);
            atomicAdd(&deg[d4.z], 1); atomicAdd(&deg[d4.w], 1);
        }
    }

    __shared__ unsigned short sA[64 * AK];    // feat tile bf16 [m][k]
    __shared__ unsigned short sBT[64 * AK];   // W1^T bf16 [n][k]
    const int t = threadIdx.x;
    const int ntile = blockIdx.x * 64;

    // stage A: 4096 float4 granules, 16 per thread (coalesced)
    #pragma unroll
    for (int i = 0; i < 16; ++i) {
        int g = t + 256 * i;
        int row = g >> 6, kq = g & 63;
        int n = ntile + row; if (n >= NN) n = NN - 1;
        float4 f = *(const float4*)&feat[(size_t)n * FIN + 4 * kq];
        ushort4 us; us.x = f2bf(f.x); us.y = f2bf(f.y); us.z = f2bf(f.z); us.w = f2bf(f.w);
        *(ushort4*)&sA[row * AK + 4 * kq] = us;
    }
    // stage B^T: 2048 8-bf16 granules, 8 per thread
    #pragma unroll
    for (int i = 0; i < 8; ++i) {
        int g = t + 256 * i;
        int row = g >> 5, c8 = g & 31;
        *(uint4*)&sBT[row * AK + 8 * c8] = *(const uint4*)&W1T[row * FIN + 8 * c8];
    }
    __syncthreads();

    const int w  = t >> 6;        // wave id -> node rows m0..m0+15
    const int l  = t & 63;
    const int lr = l & 15;        // A row / B col / D col within tile
    const int q  = l >> 4;        // quad
    const int m0 = 16 * w;

    floatx4 acc[4];
    #pragma unroll
    for (int tile = 0; tile < 4; ++tile) acc[tile] = 0.f;

    #pragma unroll
    for (int kc = 0; kc < 8; ++kc) {
        const int koff = kc * 32 + 8 * q;
        const short8 av = *(const short8*)(sA + (m0 + lr) * AK + koff);
        #pragma unroll
        for (int tile = 0; tile < 4; ++tile) {
            const short8 bv = *(const short8*)(sBT + (16 * tile + lr) * AK + koff);
            acc[tile] = __builtin_amdgcn_mfma_f32_16x16x32_bf16(av, bv, acc[tile], 0, 0, 0);
        }
    }

    // epilogue: z store + el/er (reduce over n within 16-lane groups)
    float aln[4], arn[4];
    #pragma unroll
    for (int tile = 0; tile < 4; ++tile) {
        aln[tile] = al[16 * tile + lr];
        arn[tile] = ar[16 * tile + lr];
    }
    #pragma unroll
    for (int r = 0; r < 4; ++r) {
        int mg = ntile + m0 + 4 * q + r;
        float pl = 0.f, pr = 0.f;
        #pragma unroll
        for (int tile = 0; tile < 4; ++tile) {
            float zv = acc[tile][r];
            pl += zv * aln[tile]; pr += zv * arn[tile];
        }
        #pragma unroll
        for (int off = 8; off >= 1; off >>= 1) {
            pl += __shfl_xor(pl, off);
            pr += __shfl_xor(pr, off);
        }
        if (mg < NN) {
            #pragma unroll
            for (int tile = 0; tile < 4; ++tile)
                z[(size_t)mg * HID + 16 * tile + lr] = acc[tile][r];
            if (lr == 0) { el[mg] = pl; er[mg] = pr; }
        }
    }
}

// ---------------- GEMM2: z2 = h @ W2, fused el2/er2 (fp32) ------------------
__global__ __launch_bounds__(256) void gemm2_kernel(
    const float* __restrict__ h, const float* __restrict__ W2,
    const float* __restrict__ al, const float* __restrict__ ar,
    float* __restrict__ z2, float* __restrict__ el, float* __restrict__ er)
{
    __shared__ float sh[4][64];
    const int w = threadIdx.x >> 6, lane = threadIdx.x & 63;
    const int n = blockIdx.x * 4 + w;          // NN % 4 == 0
    sh[w][lane] = h[(size_t)n * HID + lane];
    __syncthreads();
    float acc = 0.f;
    if (lane < FOUT) {
        #pragma unroll 8
        for (int k = 0; k < 64; ++k) acc += sh[w][k] * W2[k * FOUT + lane];
    }
    float pl = (lane < FOUT) ? acc * al[lane] : 0.f;
    float pr = (lane < FOUT) ? acc * ar[lane] : 0.f;
    #pragma unroll
    for (int off = 32; off >= 1; off >>= 1) { pl += __shfl_xor(pl, off); pr += __shfl_xor(pr, off); }
    if (lane == 0) { el[n] = pl; er[n] = pr; }
    if (lane < FOUT) z2[(size_t)n * FOUT + lane] = acc;
}

// ---------------- CSR build: scans ------------------------------------------
__global__ __launch_bounds__(256) void scan_reduce_kernel(
    const int* __restrict__ deg, int* __restrict__ bsum)
{
    __shared__ int tmp[256];
    int idx = blockIdx.x * 256 + threadIdx.x;
    int v = (idx < NN) ? deg[idx] : 0;
    tmp[threadIdx.x] = v; __syncthreads();
    for (int off = 128; off >= 1; off >>= 1) {
        if (threadIdx.x < off) tmp[threadIdx.x] += tmp[threadIdx.x + off];
        __syncthreads();
    }
    if (threadIdx.x == 0) bsum[blockIdx.x] = tmp[0];
}

__global__ __launch_bounds__(512) void scan_top_kernel(
    const int* __restrict__ bsum, int* __restrict__ bofs, int* __restrict__ row_ptr)
{
    __shared__ int tmp[512];
    int t = threadIdx.x;
    int v = (t < NB) ? bsum[t] : 0;
    tmp[t] = v; __syncthreads();
    for (int off = 1; off < 512; off <<= 1) {
        int x = (t >= off) ? tmp[t - off] : 0;
        __syncthreads();
        tmp[t] += x;
        __syncthreads();
    }
    int excl = tmp[t] - v;
    if (t < NB) bofs[t] = excl;
    if (t == NB - 1) row_ptr[NN] = excl + v;  // total = NE
}

// writes row_ptr; also bucket cursor init gcur[b] = bucket base
__global__ __launch_bounds__(256) void scan_final_kernel(
    const int* __restrict__ deg, const int* __restrict__ bofs,
    int* __restrict__ row_ptr, int* __restrict__ gcur)
{
    __shared__ int tmp[256];
    int t = threadIdx.x;
    int idx = blockIdx.x * 256 + t;
    int v = (idx < NN) ? deg[idx] : 0;
    tmp[t] = v; __syncthreads();
    for (int off = 1; off < 256; off <<= 1) {
        int x = (t >= off) ? tmp[t - off] : 0;
        __syncthreads();
        tmp[t] += x;
        __syncthreads();
    }
    if (idx < NN) row_ptr[idx] = bofs[blockIdx.x] + tmp[t] - v;
    if (t == 0) gcur[blockIdx.x] = bofs[blockIdx.x];   // block b == bucket b
}

// ---------------- Pass A: bucket partition (line-dense writes) --------------
// pack = (src << 8) | (dst & 255); bucket = dst >> 8
__global__ __launch_bounds__(256) void partitionA_kernel(
    const int* __restrict__ src, const int* __restrict__ dst,
    int* __restrict__ gcur, int* __restrict__ ebuck)
{
    __shared__ int hist[NBUCK];
    __shared__ int lcur[NBUCK];
    const int t = threadIdx.x;
    const int e0 = blockIdx.x * TILE_A;
    const int e1 = (e0 + TILE_A < NE) ? e0 + TILE_A : NE;

    for (int i = t; i < NBUCK; i += 256) hist[i] = 0;
    __syncthreads();
    for (int e = e0 + t; e < e1; e += 256)
        atomicAdd(&hist[dst[e] >> 8], 1);
    __syncthreads();
    for (int i = t; i < NBUCK; i += 256) {
        int hv = hist[i];
        lcur[i] = hv ? atomicAdd(&gcur[i], hv) : 0;
    }
    __syncthreads();
    for (int e = e0 + t; e < e1; e += 256) {
        int d = dst[e], s = src[e];
        int p = atomicAdd(&lcur[d >> 8], 1);
        ebuck[p] = (s << 8) | (d & 255);
    }
}

// ---------------- Pass B: per-bucket CSR scatter (LDS cursors) --------------
__global__ __launch_bounds__(256) void partitionB_kernel(
    const int* __restrict__ row_ptr, const int* __restrict__ ebuck,
    int* __restrict__ esrc)
{
    __shared__ int lcur[256];
    const int b = blockIdx.x;
    const int n0 = b << 8;
    const int n1 = (n0 + 256 < NN) ? n0 + 256 : NN;
    const int t = threadIdx.x;
    if (n0 + t < n1) lcur[t] = row_ptr[n0 + t];
    __syncthreads();
    const int r0 = row_ptr[n0], r1 = row_ptr[n1];
    for (int e = r0 + t; e < r1; e += 256) {
        int pk = ebuck[e];
        int p = atomicAdd(&lcur[pk & 255], 1);
        esrc[p] = pk >> 8;
    }
}

// ---------------- fused per-destination GAT gather -------------------------
template<int F, bool FINAL_LAYER>
__global__ __launch_bounds__(256) void gat_gather_kernel(
    const int* __restrict__ row_ptr, const int* __restrict__ esrc,
    const float* __restrict__ el, const float* __restrict__ er,
    const float* __restrict__ z, const float* __restrict__ bias,
    float* __restrict__ out)
{
    __shared__ float sw[4][64];
    __shared__ int   ssn[4][64];
    const int w = threadIdx.x >> 6, lane = threadIdx.x & 63;
    const int d = blockIdx.x * 4 + w;          // NN % 4 == 0
    const int r0 = row_ptr[d], r1 = row_ptr[d + 1];
    const int cnt = r1 - r0;
    const float erd = er[d];

    float accv = 0.f;
    float s = 0.f;

    if (cnt <= 64) {
        int sn = 0; float v = -INFINITY;
        if (lane < cnt) {
            sn = esrc[r0 + lane];
            v = el[sn] + erd;
            v = (v >= 0.f) ? v : SLOPE * v;
        }
        float m = v;
        #pragma unroll
        for (int off = 32; off >= 1; off >>= 1) m = fmaxf(m, __shfl_xor(m, off));
        float wv = (lane < cnt) ? __expf(v - m) : 0.f;
        s = wv;
        #pragma unroll
        for (int off = 32; off >= 1; off >>= 1) s += __shfl_xor(s, off);
        sw[w][lane] = wv; ssn[w][lane] = sn;   // wave-synchronous
        if (lane < F) {
            int j = 0;
            for (; j + 8 <= cnt; j += 8) {
                float acc0 = 0.f, acc1 = 0.f;
                #pragma unroll
                for (int qq = 0; qq < 8; qq += 2) {
                    float wa = sw[w][j + qq],     wb = sw[w][j + qq + 1];
                    int   sa = ssn[w][j + qq],    sb = ssn[w][j + qq + 1];
                    acc0 += wa * z[(size_t)sa * F + lane];
                    acc1 += wb * z[(size_t)sb * F + lane];
                }
                accv += acc0 + acc1;
            }
            for (; j < cnt; ++j)
                accv += sw[w][j] * z[(size_t)ssn[w][j] * F + lane];
        }
    } else {
        float m = -INFINITY;
        for (int e = r0 + lane; e < r1; e += 64) {
            float v = el[esrc[e]] + erd;
            v = (v >= 0.f) ? v : SLOPE * v;
            m = fmaxf(m, v);
        }
        #pragma unroll
        for (int off = 32; off >= 1; off >>= 1) m = fmaxf(m, __shfl_xor(m, off));
        for (int base = r0; base < r1; base += 64) {
            int e = base + lane;
            float wv = 0.f; int sn = 0;
            if (e < r1) {
                sn = esrc[e];
                float v = el[sn] + erd;
                v = (v >= 0.f) ? v : SLOPE * v;
                wv = __expf(v - m);
            }
            sw[w][lane] = wv; ssn[w][lane] = sn;
            s += wv;
            int c = r1 - base; if (c > 64) c = 64;
            if (lane < F) {
                for (int j = 0; j < c; ++j)
                    accv += sw[w][j] * z[(size_t)ssn[w][j] * F + lane];
            }
        }
        #pragma unroll
        for (int off = 32; off >= 1; off >>= 1) s += __shfl_xor(s, off);
    }

    float res = (cnt > 0) ? (accv / s) : 0.f;

    if (!FINAL_LAYER) {
        if (lane < F) {
            float v = res + bias[lane];
            out[(size_t)d * F + lane] = (v > 0.f) ? v : 0.f;
        }
    } else {
        float v = (lane < F) ? res + bias[lane] : -INFINITY;
        float mx = v;
        #pragma unroll
        for (int off = 32; off >= 1; off >>= 1) mx = fmaxf(mx, __shfl_xor(mx, off));
        float ex = (lane < F) ? __expf(v - mx) : 0.f;
        float sm = ex;
        #pragma unroll
        for (int off = 32; off >= 1; off >>= 1) sm += __shfl_xor(sm, off);
        if (lane < F) out[(size_t)d * F + lane] = v - mx - __logf(sm);
    }
}

extern "C" void kernel_launch(void* const* d_in, const int* in_sizes, int n_in,
                              void* d_out, int out_size, void* d_ws, size_t ws_size,
                              hipStream_t stream) {
    const float* feat = (const float*)d_in[0];
    const int*   src  = (const int*)d_in[1];
    const int*   dst  = (const int*)d_in[2];
    const float* W1   = (const float*)d_in[3];
    const float* b1   = (const float*)d_in[4];
    const float* al1  = (const float*)d_in[5];
    const float* ar1  = (const float*)d_in[6];
    const float* W2   = (const float*)d_in[7];
    const float* b2   = (const float*)d_in[8];
    const float* al2  = (const float*)d_in[9];
    const float* ar2  = (const float*)d_in[10];
    float* out = (float*)d_out;

    float* ws    = (float*)d_ws;
    float* z1    = ws;                          // NN*64 (reused for z2)
    float* h     = z1 + (size_t)NN * HID;       // NN*64
    float* el1   = h + (size_t)NN * HID;
    float* er1   = el1 + NN;
    float* el2   = er1 + NN;
    float* er2   = el2 + NN;
    int*   deg   = (int*)(er2 + NN);            // NN
    int*   rowp  = deg + NN;                    // NN+1
    int*   bsum  = rowp + NN + 1;               // NB
    int*   bofs  = bsum + NB;                   // NB
    int*   gcur  = bofs + NB;                   // NBUCK
    int*   esrc  = gcur + NBUCK;                // NE
    unsigned short* w1t = (unsigned short*)(esrc + NE);  // FIN*HID bf16
    int*   ebuck = (int*)h;                     // NE, dead before gather1 writes h
    float* z2    = z1;

    hipMemsetAsync(deg, 0, NN * sizeof(int), stream);

    // ---- W1^T bf16 prep + layer-1 MFMA GEMM with fused dst-histogram ----
    w1t_kernel<<<(FIN * HID + 255) / 256, 256, 0, stream>>>(W1, w1t);
    gemm1_kernel<<<(NN + 63) / 64, 256, 0, stream>>>(feat, w1t, al1, ar1, dst, deg, z1, el1, er1);

    // ---- CSR build ----
    scan_reduce_kernel<<<NB, 256, 0, stream>>>(deg, bsum);
    scan_top_kernel<<<1, 512, 0, stream>>>(bsum, bofs, rowp);
    scan_final_kernel<<<NB, 256, 0, stream>>>(deg, bofs, rowp, gcur);
    partitionA_kernel<<<NWG_A, 256, 0, stream>>>(src, dst, gcur, ebuck);
    partitionB_kernel<<<NBUCK, 256, 0, stream>>>(rowp, ebuck, esrc);

    // ---- layer 1 gather ----
    gat_gather_kernel<HID, false><<<NN / 4, 256, 0, stream>>>(rowp, esrc, el1, er1, z1, b1, h);

    // ---- layer 2 ----
    gemm2_kernel<<<NN / 4, 256, 0, stream>>>(h, W2, al2, ar2, z2, el2, er2);
    gat_gather_kernel<FOUT, true><<<NN / 4, 256, 0, stream>>>(rowp, esrc, el2, er2, z2, b2, out);
}